// Round 5
// baseline (770.605 us; speedup 1.0000x reference)
//
#include <hip/hip_runtime.h>
#include <hip/hip_bf16.h>
#include <math.h>

#define D    1024
#define NQ   512
#define NKV  1024
#define BATCH 8
#define NH   16
#define HD   64
#define FFD  4096

typedef short bf16x8 __attribute__((ext_vector_type(8)));   // 8 bf16 (4 VGPRs)
typedef float f32x4  __attribute__((ext_vector_type(4)));

static __device__ __forceinline__ float bf2f(__hip_bfloat16 x){ return __bfloat162float(x); }
static __device__ __forceinline__ unsigned short f2bbits(float f){
    __hip_bfloat16 h = __float2bfloat16(f);
    return *(unsigned short*)&h;
}

// async global->LDS, 16B per lane; LDS dest = wave-uniform base + lane*16 (HW).
static __device__ __forceinline__ void gload_lds16(const __hip_bfloat16* g, __hip_bfloat16* l){
    __builtin_amdgcn_global_load_lds(
        (const __attribute__((address_space(1))) void*)g,
        (__attribute__((address_space(3))) void*)l,
        16, 0, 0);
}

// ---------------- f32 -> bf16 weight conversion ----------------
__global__ __launch_bounds__(256) void cvt_w_kernel(const float* __restrict__ in,
                                                    __hip_bfloat16* __restrict__ out, int n)
{
    int i = blockIdx.x*256 + threadIdx.x;
    if (i < n) out[i] = __float2bfloat16(in[i]);
}

// ---------------- LayerNorm (f32 in -> bf16 out), 256 thr, row = 1024 ----------------
__global__ __launch_bounds__(256) void ln_kernel(
    const float* __restrict__ x, const float* __restrict__ gamma, const float* __restrict__ beta,
    __hip_bfloat16* __restrict__ out)
{
    int row = blockIdx.x, t = threadIdx.x;
    __shared__ float wsum[4];
    __shared__ float stat[2];
    float4 v = *(const float4*)&x[(size_t)row*D + t*4];
    float s = v.x+v.y+v.z+v.w;
    #pragma unroll
    for (int o=32;o>0;o>>=1) s += __shfl_down(s, o);
    if ((t&63)==0) wsum[t>>6] = s;
    __syncthreads();
    if (t==0) stat[0] = (wsum[0]+wsum[1]+wsum[2]+wsum[3])*(1.f/D);
    __syncthreads();
    float mu = stat[0];
    float d0=v.x-mu, d1=v.y-mu, d2=v.z-mu, d3=v.w-mu;
    float s2 = d0*d0+d1*d1+d2*d2+d3*d3;
    #pragma unroll
    for (int o=32;o>0;o>>=1) s2 += __shfl_down(s2, o);
    if ((t&63)==0) wsum[t>>6] = s2;
    __syncthreads();
    if (t==0) stat[1] = rsqrtf((wsum[0]+wsum[1]+wsum[2]+wsum[3])*(1.f/D) + 1e-5f);
    __syncthreads();
    float rs = stat[1];
    const float4 g = *(const float4*)&gamma[t*4];
    const float4 b = *(const float4*)&beta[t*4];
    union { unsigned short u[4]; short4 s4; } pk;
    pk.u[0]=f2bbits(d0*rs*g.x+b.x); pk.u[1]=f2bbits(d1*rs*g.y+b.y);
    pk.u[2]=f2bbits(d2*rs*g.z+b.z); pk.u[3]=f2bbits(d3*rs*g.w+b.w);
    *(short4*)&out[(size_t)row*D + t*4] = pk.s4;
}

// ---------------- MFMA GEMM core: 128x128 tile, BK=32, 4 waves, DOUBLE-BUFFERED ----------
#define BM 128
#define BN 128
#define BK 32

static __device__ __forceinline__ void stage128(
    const __hip_bfloat16* __restrict__ A, const __hip_bfloat16* __restrict__ W,
    int K, int bm, int bn, int k0,
    __hip_bfloat16* as, __hip_bfloat16* bs, int w, int srow, int scol)
{
    #pragma unroll
    for (int rep=0; rep<2; rep++){
        int ti = (w<<1) + rep;   // wave-uniform 0..7; instr covers 16 rows x 32 cols
        gload_lds16(&A[(size_t)(bm + ti*16 + srow)*K + k0 + scol], &as[ti*16*BK]);
        gload_lds16(&W[(size_t)(bn + ti*16 + srow)*K + k0 + scol], &bs[ti*16*BK]);
    }
}

static __device__ __forceinline__ void compute128(
    const __hip_bfloat16* as, const __hip_bfloat16* bs,
    int wm, int wn, int quad, int l16, f32x4 acc[4][4])
{
    bf16x8 af[4], bfr[4];
    #pragma unroll
    for (int i=0;i<4;i++) af[i]  = *(const bf16x8*)&as[(wm + 16*i + l16)*BK + quad*8];
    #pragma unroll
    for (int j=0;j<4;j++) bfr[j] = *(const bf16x8*)&bs[(wn + 16*j + l16)*BK + quad*8];
    #pragma unroll
    for (int i=0;i<4;i++)
        #pragma unroll
        for (int j=0;j<4;j++)
            acc[i][j] = __builtin_amdgcn_mfma_f32_16x16x32_bf16(af[i], bfr[j], acc[i][j], 0, 0, 0);
}

static __device__ __forceinline__ void gemm_loop(
    const __hip_bfloat16* __restrict__ A, const __hip_bfloat16* __restrict__ W,
    int K, int bm, int bn,
    __hip_bfloat16* As0, __hip_bfloat16* Bs0, __hip_bfloat16* As1, __hip_bfloat16* Bs1,
    f32x4 acc[4][4])
{
    const int t = threadIdx.x;
    const int w = t >> 6, lane = t & 63;
    const int quad = lane >> 4, l16 = lane & 15;
    const int wm = (w >> 1) * 64, wn = (w & 1) * 64;
    const int srow = lane >> 2, scol = (lane & 3) << 3;

    stage128(A, W, K, bm, bn, 0, As0, Bs0, w, srow, scol);
    __syncthreads();
    const int nt = K >> 5;                 // K in {1024,4096} -> nt even
    for (int ts = 0; ts < nt; ts += 2){
        stage128(A, W, K, bm, bn, (ts+1)<<5, As1, Bs1, w, srow, scol);   // in flight during MFMA
        compute128(As0, Bs0, wm, wn, quad, l16, acc);
        __syncthreads();
        if (ts + 2 < nt)
            stage128(A, W, K, bm, bn, (ts+2)<<5, As0, Bs0, w, srow, scol);
        compute128(As1, Bs1, wm, wn, quad, l16, acc);
        __syncthreads();
    }
}

// ---------------- generic GEMM (outproj / FF1 / FF2): C = A * Wb^T + bias (+epilogue) ----
__global__ __launch_bounds__(256) void gemm_mfma_kernel(
    const __hip_bfloat16* __restrict__ A, const __hip_bfloat16* __restrict__ Wb,
    const float* __restrict__ bias, int biasOff,
    const float* __restrict__ residIn, const float* __restrict__ residF,
    float* __restrict__ Cf, __hip_bfloat16* __restrict__ Cb,
    int M, int N, int K, int gelu)
{
    __shared__ __hip_bfloat16 As0[BM*BK], Bs0[BN*BK], As1[BM*BK], Bs1[BN*BK];
    int bm = blockIdx.y * BM, bn = blockIdx.x * BN;
    f32x4 acc[4][4];
    #pragma unroll
    for (int i=0;i<4;i++)
        #pragma unroll
        for (int j=0;j<4;j++) acc[i][j] = (f32x4){0.f,0.f,0.f,0.f};

    gemm_loop(A, Wb, K, bm, bn, As0, Bs0, As1, Bs1, acc);

    const int t = threadIdx.x;
    const int w = t >> 6, lane = t & 63;
    const int quad = lane >> 4, l16 = lane & 15;
    const int wm = (w >> 1) * 64, wn = (w & 1) * 64;
    // C/D layout: col = lane&15, row = quad*4 + reg   [m89-verified]
    #pragma unroll
    for (int i=0;i<4;i++){
        #pragma unroll
        for (int j=0;j<4;j++){
            int colg = bn + wn + 16*j + l16;
            float bv = bias[biasOff + colg];
            #pragma unroll
            for (int r=0;r<4;r++){
                int rowg = bm + wm + 16*i + quad*4 + r;
                float vv = acc[i][j][r] + bv;
                if (gelu) vv = 0.5f*vv*(1.f + erff(vv*0.70710678118654752f));
                size_t idx = (size_t)rowg*N + colg;
                if (residIn) vv += residIn[idx];
                if (residF)  vv += residF[idx];
                if (Cf) Cf[idx] = vv;
                if (Cb) Cb[idx] = __float2bfloat16(vv);
            }
        }
    }
}

// ---------------- merged QKV projection: one dispatch, 1280 blocks (~5/CU) -------------
__global__ __launch_bounds__(256) void qkv_kernel(
    const __hip_bfloat16* __restrict__ qln, const __hip_bfloat16* __restrict__ kvln,
    const __hip_bfloat16* __restrict__ wip, const float* __restrict__ ipb,
    __hip_bfloat16* __restrict__ qb, __hip_bfloat16* __restrict__ kb,
    __hip_bfloat16* __restrict__ vbT)
{
    __shared__ __hip_bfloat16 As0[BM*BK], Bs0[BN*BK], As1[BM*BK], Bs1[BN*BK];
    int id = blockIdx.x;
    const __hip_bfloat16 *A, *W;
    int bm, bn, isq;
    if (id < 1024){ isq = 0; A = kvln; W = wip + (size_t)D*D; bn = (id & 15)*BN; bm = (id >> 4)*BM; }
    else { int qid = id - 1024; isq = 1; A = qln; W = wip; bn = (qid & 7)*BN; bm = (qid >> 3)*BM; }

    f32x4 acc[4][4];
    #pragma unroll
    for (int i=0;i<4;i++)
        #pragma unroll
        for (int j=0;j<4;j++) acc[i][j] = (f32x4){0.f,0.f,0.f,0.f};

    gemm_loop(A, W, 1024, bm, bn, As0, Bs0, As1, Bs1, acc);

    const int t = threadIdx.x;
    const int w = t >> 6, lane = t & 63;
    const int quad = lane >> 4, l16 = lane & 15;
    const int wm = (w >> 1) * 64, wn = (w & 1) * 64;
    #pragma unroll
    for (int i=0;i<4;i++){
        #pragma unroll
        for (int j=0;j<4;j++){
            int colg = bn + wn + 16*j + l16;
            float bv = ipb[(isq ? 0 : D) + colg];
            if (isq){
                #pragma unroll
                for (int r=0;r<4;r++){
                    int rowg = bm + wm + 16*i + quad*4 + r;
                    qb[(size_t)rowg*D + colg] = __float2bfloat16(acc[i][j][r] + bv);
                }
            } else if (colg < 1024){
                #pragma unroll
                for (int r=0;r<4;r++){
                    int rowg = bm + wm + 16*i + quad*4 + r;
                    kb[(size_t)rowg*D + colg] = __float2bfloat16(acc[i][j][r] + bv);
                }
            } else {
                // V head-transposed: vbT[((b*NH+h)*HD+d)*NKV + kv], 4 consecutive kv packed
                union { unsigned short u[4]; short4 s4; } pk;
                #pragma unroll
                for (int r=0;r<4;r++) pk.u[r] = f2bbits(acc[i][j][r] + bv);
                int rowg0 = bm + wm + 16*i + quad*4;     // kv-token row, multiple of 4
                int bb = rowg0 >> 10, kvi = rowg0 & 1023;
                int c = colg - 1024, hh = c >> 6, dd = c & 63;
                *(short4*)&vbT[(((size_t)bb*NH + hh)*HD + dd)*NKV + kvi] = pk.s4;
            }
        }
    }
}

// ---------------- MFMA attention, head-split for occupancy ----------------
// grid (BATCH, NQ/16, HSPLIT=4); 512 thr = 8 waves; block handles HPB=4 heads.
// 4 blocks/CU (LDS ~39KB each) -> 32 waves/CU; 4 independent latency chains.
// attn_mean: per-block partial over its heads, atomicAdd into pre-zeroed out_attn.
// Barrier schedule: 4 per head (B1 max-red, B2 sum-red+P-write, B3 pvred, loop).
#define QT 16
#define HSPLIT 4
#define HPB (NH/HSPLIT)
#define PLD (NKV + 8)    // P row stride (elements); 2064B rows de-stride LDS banks
__global__ __launch_bounds__(512) void attn_kernel(
    const __hip_bfloat16* __restrict__ q, const __hip_bfloat16* __restrict__ k,
    const __hip_bfloat16* __restrict__ vt, const void* __restrict__ mask,
    __hip_bfloat16* __restrict__ ctx, float* __restrict__ attn_out)
{
    const int t = threadIdx.x;
    const int w = t >> 6;            // wave 0..7
    const int lane = t & 63;
    const int g = lane >> 4;         // quad
    const int l16 = lane & 15;       // q-row for S^T / P / PV-cols
    const int b  = blockIdx.x;       // batch on grid.x -> XCD-local K/V
    const int q0 = blockIdx.y * QT;
    const int h0 = blockIdx.z * HPB;

    __shared__ __hip_bfloat16 P[QT*PLD];     // P[q][kv]
    __shared__ float pvred[4*16*20];         // [mt][q][d-pad20] partial ctx^T (kv-half 1)
    __shared__ float red1[8*16];             // per-wave row max
    __shared__ float red2[8*16];             // per-wave row sum
    __shared__ int m8s;

    if (t==0) m8s = 0;
    __syncthreads();
    if (t < 256){ unsigned wd = ((const unsigned*)mask)[t]; if (wd > 1u) atomicOr(&m8s, 1); }
    __syncthreads();
    const bool m8 = m8s != 0;

    // per-lane mask bits: kv = w*128 + kt*16 + 4*g + r  (matches S^T register layout)
    unsigned mbits = 0;
    #pragma unroll
    for (int kt=0;kt<8;kt++){
        #pragma unroll
        for (int r=0;r<4;r++){
            size_t mi = (size_t)b*NKV + w*128 + kt*16 + 4*g + r;
            int mv = m8 ? (int)((const unsigned char*)mask)[mi] : ((const int*)mask)[mi];
            if (mv) mbits |= (1u << (kt*4+r));
        }
    }

    float amean[8][4];
    #pragma unroll
    for (int kt=0;kt<8;kt++)
        #pragma unroll
        for (int r=0;r<4;r++) amean[kt][r] = 0.f;

    const int mt = w >> 1;           // PV: d-tile 0..3
    const int kvh = w & 1;           // PV: kv half
    const __hip_bfloat16* qrow = &q[((size_t)(b*NQ + q0 + l16))*D];

    for (int hh=0; hh<HPB; hh++){
        const int h = h0 + hh;
        // ---- S^T = K @ Q^T  (per wave: 8 kv-tiles x K=64) ----
        bf16x8 bq0 = *(const bf16x8*)&qrow[h*HD + g*8];
        bf16x8 bq1 = *(const bf16x8*)&qrow[h*HD + 32 + g*8];
        f32x4 s[8];
        #pragma unroll
        for (int kt=0;kt<8;kt++){
            const __hip_bfloat16* kp = &k[((size_t)(b*NKV + w*128 + kt*16 + l16))*D + h*HD];
            bf16x8 a0 = *(const bf16x8*)&kp[g*8];
            bf16x8 a1 = *(const bf16x8*)&kp[32 + g*8];
            f32x4 z = (f32x4){0.f,0.f,0.f,0.f};
            z = __builtin_amdgcn_mfma_f32_16x16x32_bf16(a0, bq0, z, 0, 0, 0);
            z = __builtin_amdgcn_mfma_f32_16x16x32_bf16(a1, bq1, z, 0, 0, 0);
            s[kt] = z;
        }
        // ---- scale + mask + row max ----
        float lmax = -3.0e38f;
        #pragma unroll
        for (int kt=0;kt<8;kt++){
            #pragma unroll
            for (int r=0;r<4;r++){
                float sv = ((mbits >> (kt*4+r)) & 1u) ? -3.0e38f : s[kt][r]*0.125f;
                s[kt][r] = sv;
                lmax = fmaxf(lmax, sv);
            }
        }
        lmax = fmaxf(lmax, __shfl_xor(lmax, 16));
        lmax = fmaxf(lmax, __shfl_xor(lmax, 32));
        if (lane < 16) red1[w*16 + l16] = lmax;
        __syncthreads();                       // B1: max reduction
        float m = red1[l16];
        #pragma unroll
        for (int w2=1; w2<8; w2++) m = fmaxf(m, red1[w2*16 + l16]);
        // ---- exp + P-write (unnormalized bf16) + row sum ----
        float lsum = 0.f;
        #pragma unroll
        for (int kt=0;kt<8;kt++){
            union { unsigned short u[4]; short4 s4; } pk;
            #pragma unroll
            for (int r=0;r<4;r++){
                float e = __expf(s[kt][r] - m);
                s[kt][r] = e;
                lsum += e;
                pk.u[r] = f2bbits(e);
            }
            *(short4*)&P[l16*PLD + w*128 + kt*16 + 4*g] = pk.s4;
        }
        lsum += __shfl_xor(lsum, 16);
        lsum += __shfl_xor(lsum, 32);
        if (lane < 16) red2[w*16 + l16] = lsum;
        __syncthreads();                       // B2: sum reduction + P visible
        float tot = red2[l16];
        #pragma unroll
        for (int w2=1; w2<8; w2++) tot += red2[w2*16 + l16];
        float inv = 1.f/tot;
        float ai  = inv * (1.f/NH);
        #pragma unroll
        for (int kt=0;kt<8;kt++)
            #pragma unroll
            for (int r=0;r<4;r++) amean[kt][r] += s[kt][r]*ai;
        // ---- PV: ctx^T[d,q] = V^T[d,:] @ P[q,:]^T ; wave = (d-tile mt, kv-half kvh) ----
        f32x4 pv = (f32x4){0.f,0.f,0.f,0.f};
        const __hip_bfloat16* vrow = &vt[(((size_t)(b*NH + h))*HD + mt*16 + l16)*NKV + kvh*512];
        #pragma unroll
        for (int ks=0;ks<16;ks++){
            bf16x8 av = *(const bf16x8*)&vrow[ks*32 + g*8];
            bf16x8 bp = *(const bf16x8*)&P[l16*PLD + kvh*512 + ks*32 + g*8];
            pv = __builtin_amdgcn_mfma_f32_16x16x32_bf16(av, bp, pv, 0, 0, 0);
        }
        if (kvh){
            *(f32x4*)&pvred[(mt*16 + l16)*20 + 4*g] = pv;
        }
        __syncthreads();                       // B3: pvred visible; P reads done
        if (!kvh){
            const f32x4 other = *(const f32x4*)&pvred[(mt*16 + l16)*20 + 4*g];
            union { unsigned short u[4]; short4 s4; } pk;
            #pragma unroll
            for (int r=0;r<4;r++) pk.u[r] = f2bbits((pv[r] + other[r]) * inv);
            *(short4*)&ctx[((size_t)(b*NQ + q0 + l16))*D + h*HD + mt*16 + 4*g] = pk.s4;
        }
        // next head's red1 write is safe: this head's red1 reads consumed before B2
    }
    // ---- attn-mean partial: atomicAdd into pre-zeroed out_attn ----
    float* ao = attn_out + ((size_t)(b*NQ + q0 + l16))*NKV;
    #pragma unroll
    for (int kt=0;kt<8;kt++)
        #pragma unroll
        for (int r=0;r<4;r++)
            atomicAdd(&ao[w*128 + kt*16 + 4*g + r], amean[kt][r]);
}

// ---------------- sentinel fill ----------------
__global__ __launch_bounds__(256) void fill_f32_kernel(float* __restrict__ p, float val, long n){
    size_t i = (size_t)blockIdx.x*256 + threadIdx.x;
    if ((long)i < n) p[i] = val;
}

extern "C" void kernel_launch(void* const* d_in, const int* in_sizes, int n_in,
                              void* d_out, int out_size, void* d_ws, size_t ws_size,
                              hipStream_t stream)
{
    const float* query     = (const float*)d_in[0];
    const float* key_value = (const float*)d_in[1];
    const void*  mask      = d_in[2];
    const float* nq_gamma  = (const float*)d_in[3];
    const float* nq_beta   = (const float*)d_in[4];
    const float* nkv_gamma = (const float*)d_in[5];
    const float* nkv_beta  = (const float*)d_in[6];
    const float* ipw       = (const float*)d_in[7];
    const float* ipb       = (const float*)d_in[8];
    const float* out_w     = (const float*)d_in[9];
    const float* out_b     = (const float*)d_in[10];
    const float* nffg      = (const float*)d_in[11];
    const float* nffb      = (const float*)d_in[12];
    const float* ff1w      = (const float*)d_in[13];
    const float* ff1b      = (const float*)d_in[14];
    const float* ff2w      = (const float*)d_in[15];
    const float* ff2b      = (const float*)d_in[16];

    float* out_x = (float*)d_out;
    // ---- host-side shape checks (proven in r6/r8; keep as guard) ----
    long Dn  = (n_in > 3)  ? in_sizes[3]  : 0;
    long FFn = (n_in > 14) ? in_sizes[14] : 0;
    long Rq=0, Rkv=0, Nkvd=0, Bd=0, Nqd=0;
    auto derive = [&](long Sq_, long Skv_)->bool{
        if (Dn <= 0 || Sq_ <= 0 || Skv_ <= 0) return false;
        if (Sq_ % Dn || Skv_ % Dn) return false;
        Rq = Sq_/Dn; Rkv = Skv_/Dn;
        long num = (long)out_size - Rq*Dn;
        if (Rq <= 0 || num <= 0 || num % Rq) return false;
        Nkvd = num / Rq;
        if (Nkvd <= 0 || Rkv % Nkvd) return false;
        Bd = Rkv / Nkvd;
        if (Bd <= 0 || Rq % Bd) return false;
        Nqd = Rq / Bd;
        if ((long)in_sizes[2] != Rkv) return false;
        return true;
    };
    int sentinel = 0;
    if (n_in != 17) sentinel = 600;
    else if (!derive(in_sizes[0], in_sizes[1])) sentinel = 300;
    if (!sentinel && !(Dn==1024 && FFn==4096 && Bd==8 && Nqd==512 && Nkvd==1024)) sentinel = 500;
    if (!sentinel && ws_size < ((size_t)88<<20)) sentinel = 400;
    if (sentinel){
        long n = out_size;
        fill_f32_kernel<<<(unsigned)((n+255)/256), 256, 0, stream>>>(out_x, (float)sentinel, n);
        return;
    }

    float* out_attn = out_x + (size_t)BATCH*NQ*D;

    // Workspace map (bytes), peak 88 MB, lifetimes checked:
    //  [0,6)   wip bf16 (3M)      live all launch
    //  [6,8)   wout bf16 (1M)     live all launch
    //  [8,16)  wff1 bf16 (4M)     live all launch
    //  [16,24) wff2 bf16 (4M)     live all launch
    //  [24,32) qln bf16  -> dead after qkv    -> ctx bf16 (attn)
    //  [32,48) kvln bf16 -> dead after qkv    -> x1 f32 (outproj)
    //  [48,56) qb bf16   -> dead after attn   -> hln bf16
    //  [56,72) kb bf16   -> dead after attn   -> hge bf16 lower
    //  [72,88) vbT bf16  -> dead after attn   -> hge bf16 upper
    char* Wc = (char*)d_ws;
    __hip_bfloat16* wip  = (__hip_bfloat16*)(Wc);
    __hip_bfloat16* wout = (__hip_bfloat16*)(Wc + ((size_t)6<<20));
    __hip_bfloat16* wff1 = (__hip_bfloat16*)(Wc + ((size_t)8<<20));
    __hip_bfloat16* wff2 = (__hip_bfloat16*)(Wc + ((size_t)16<<20));
    __hip_bfloat16* qln  = (__hip_bfloat16*)(Wc + ((size_t)24<<20));
    __hip_bfloat16* kvln = (__hip_bfloat16*)(Wc + ((size_t)32<<20));
    __hip_bfloat16* qb   = (__hip_bfloat16*)(Wc + ((size_t)48<<20));
    __hip_bfloat16* kb   = (__hip_bfloat16*)(Wc + ((size_t)56<<20));
    __hip_bfloat16* vbT  = (__hip_bfloat16*)(Wc + ((size_t)72<<20));
    __hip_bfloat16* ctx  = (__hip_bfloat16*)(Wc + ((size_t)24<<20));
    float*          x1   = (float*)(Wc + ((size_t)32<<20));
    __hip_bfloat16* hln  = (__hip_bfloat16*)(Wc + ((size_t)48<<20));
    __hip_bfloat16* hge  = (__hip_bfloat16*)(Wc + ((size_t)56<<20));

    // 0) weight conversion f32->bf16
    cvt_w_kernel<<<(3*1024*1024+255)/256, 256, 0, stream>>>(ipw,  wip,  3*1024*1024);
    cvt_w_kernel<<<(1024*1024+255)/256,   256, 0, stream>>>(out_w, wout, 1024*1024);
    cvt_w_kernel<<<(4*1024*1024+255)/256, 256, 0, stream>>>(ff1w, wff1, 4*1024*1024);
    cvt_w_kernel<<<(4*1024*1024+255)/256, 256, 0, stream>>>(ff2w, wff2, 4*1024*1024);
    // 1) LayerNorms -> bf16
    ln_kernel<<<BATCH*NQ,  256, 0, stream>>>(query,     nq_gamma,  nq_beta,  qln);
    ln_kernel<<<BATCH*NKV, 256, 0, stream>>>(key_value, nkv_gamma, nkv_beta, kvln);
    // 2) merged QKV projection (1280 blocks; V written head-transposed [b][h][d][kv])
    qkv_kernel<<<1280, 256, 0, stream>>>(qln, kvln, wip, ipb, qb, kb, vbT);
    // 3) Attention: zero attn-mean, then head-split MFMA attention with atomic partials
    fill_f32_kernel<<<(unsigned)(((long)BATCH*NQ*NKV+255)/256), 256, 0, stream>>>(out_attn, 0.f, (long)BATCH*NQ*NKV);
    attn_kernel<<<dim3(BATCH, NQ/QT, HSPLIT), 512, 0, stream>>>(qb, kb, vbT, mask, ctx, out_attn);
    // 4) Output projection + residual(query) -> x1 f32
    gemm_mfma_kernel<<<dim3(8,32),  256, 0, stream>>>(ctx, wout, out_b, 0, query, nullptr, x1, nullptr, 4096, 1024, 1024, 0);
    // 5) FFN LN -> hln bf16
    ln_kernel<<<4096, 256, 0, stream>>>(x1, nffg, nffb, hln);
    // 6) FF1 + GELU -> hge bf16
    gemm_mfma_kernel<<<dim3(32,32), 256, 0, stream>>>(hln, wff1, ff1b, 0, nullptr, nullptr, nullptr, hge, 4096, 4096, 1024, 1);
    // 7) FF2 + residual(x1) -> out_x f32
    gemm_mfma_kernel<<<dim3(8,32),  256, 0, stream>>>(hge, wff2, ff2b, 0, nullptr, x1, out_x, nullptr, 4096, 1024, 4096, 0);
}

// Round 6
// 597.535 us; speedup vs baseline: 1.2896x; 1.2896x over previous
//
#include <hip/hip_runtime.h>
#include <hip/hip_bf16.h>
#include <math.h>

#define D    1024
#define NQ   512
#define NKV  1024
#define BATCH 8
#define NH   16
#define HD   64
#define FFD  4096

typedef short bf16x8 __attribute__((ext_vector_type(8)));   // 8 bf16 (4 VGPRs)
typedef float f32x4  __attribute__((ext_vector_type(4)));

static __device__ __forceinline__ float bf2f(__hip_bfloat16 x){ return __bfloat162float(x); }
static __device__ __forceinline__ unsigned short f2bbits(float f){
    __hip_bfloat16 h = __float2bfloat16(f);
    return *(unsigned short*)&h;
}

// async global->LDS, 16B per lane; LDS dest = wave-uniform base + lane*16 (HW).
static __device__ __forceinline__ void gload_lds16(const __hip_bfloat16* g, __hip_bfloat16* l){
    __builtin_amdgcn_global_load_lds(
        (const __attribute__((address_space(1))) void*)g,
        (__attribute__((address_space(3))) void*)l,
        16, 0, 0);
}

// ---------------- f32 -> bf16 weight conversion ----------------
__global__ __launch_bounds__(256) void cvt_w_kernel(const float* __restrict__ in,
                                                    __hip_bfloat16* __restrict__ out, int n)
{
    int i = blockIdx.x*256 + threadIdx.x;
    if (i < n) out[i] = __float2bfloat16(in[i]);
}

// ---------------- LayerNorm (f32 in -> bf16 out), 256 thr, row = 1024 ----------------
__global__ __launch_bounds__(256) void ln_kernel(
    const float* __restrict__ x, const float* __restrict__ gamma, const float* __restrict__ beta,
    __hip_bfloat16* __restrict__ out)
{
    int row = blockIdx.x, t = threadIdx.x;
    __shared__ float wsum[4];
    __shared__ float stat[2];
    float4 v = *(const float4*)&x[(size_t)row*D + t*4];
    float s = v.x+v.y+v.z+v.w;
    #pragma unroll
    for (int o=32;o>0;o>>=1) s += __shfl_down(s, o);
    if ((t&63)==0) wsum[t>>6] = s;
    __syncthreads();
    if (t==0) stat[0] = (wsum[0]+wsum[1]+wsum[2]+wsum[3])*(1.f/D);
    __syncthreads();
    float mu = stat[0];
    float d0=v.x-mu, d1=v.y-mu, d2=v.z-mu, d3=v.w-mu;
    float s2 = d0*d0+d1*d1+d2*d2+d3*d3;
    #pragma unroll
    for (int o=32;o>0;o>>=1) s2 += __shfl_down(s2, o);
    if ((t&63)==0) wsum[t>>6] = s2;
    __syncthreads();
    if (t==0) stat[1] = rsqrtf((wsum[0]+wsum[1]+wsum[2]+wsum[3])*(1.f/D) + 1e-5f);
    __syncthreads();
    float rs = stat[1];
    const float4 g = *(const float4*)&gamma[t*4];
    const float4 b = *(const float4*)&beta[t*4];
    union { unsigned short u[4]; short4 s4; } pk;
    pk.u[0]=f2bbits(d0*rs*g.x+b.x); pk.u[1]=f2bbits(d1*rs*g.y+b.y);
    pk.u[2]=f2bbits(d2*rs*g.z+b.z); pk.u[3]=f2bbits(d3*rs*g.w+b.w);
    *(short4*)&out[(size_t)row*D + t*4] = pk.s4;
}

// ---------------- MFMA GEMM core: 128x128 tile, BK=32, 4 waves, DOUBLE-BUFFERED ----------
#define BM 128
#define BN 128
#define BK 32

static __device__ __forceinline__ void stage128(
    const __hip_bfloat16* __restrict__ A, const __hip_bfloat16* __restrict__ W,
    int K, int bm, int bn, int k0,
    __hip_bfloat16* as, __hip_bfloat16* bs, int w, int srow, int scol)
{
    #pragma unroll
    for (int rep=0; rep<2; rep++){
        int ti = (w<<1) + rep;   // wave-uniform 0..7; instr covers 16 rows x 32 cols
        gload_lds16(&A[(size_t)(bm + ti*16 + srow)*K + k0 + scol], &as[ti*16*BK]);
        gload_lds16(&W[(size_t)(bn + ti*16 + srow)*K + k0 + scol], &bs[ti*16*BK]);
    }
}

static __device__ __forceinline__ void compute128(
    const __hip_bfloat16* as, const __hip_bfloat16* bs,
    int wm, int wn, int quad, int l16, f32x4 acc[4][4])
{
    bf16x8 af[4], bfr[4];
    #pragma unroll
    for (int i=0;i<4;i++) af[i]  = *(const bf16x8*)&as[(wm + 16*i + l16)*BK + quad*8];
    #pragma unroll
    for (int j=0;j<4;j++) bfr[j] = *(const bf16x8*)&bs[(wn + 16*j + l16)*BK + quad*8];
    #pragma unroll
    for (int i=0;i<4;i++)
        #pragma unroll
        for (int j=0;j<4;j++)
            acc[i][j] = __builtin_amdgcn_mfma_f32_16x16x32_bf16(af[i], bfr[j], acc[i][j], 0, 0, 0);
}

// K-range [kBeg,kEnd) of a row-major K-stride matrix pair; supports split-K.
static __device__ __forceinline__ void gemm_loop(
    const __hip_bfloat16* __restrict__ A, const __hip_bfloat16* __restrict__ W,
    int K, int bm, int bn, int kBeg, int kEnd,
    __hip_bfloat16* As0, __hip_bfloat16* Bs0, __hip_bfloat16* As1, __hip_bfloat16* Bs1,
    f32x4 acc[4][4])
{
    const int t = threadIdx.x;
    const int w = t >> 6, lane = t & 63;
    const int quad = lane >> 4, l16 = lane & 15;
    const int wm = (w >> 1) * 64, wn = (w & 1) * 64;
    const int srow = lane >> 2, scol = (lane & 3) << 3;

    stage128(A, W, K, bm, bn, kBeg, As0, Bs0, w, srow, scol);
    __syncthreads();
    const int nt = (kEnd - kBeg) >> 5;     // even for all our shapes
    for (int ts = 0; ts < nt; ts += 2){
        stage128(A, W, K, bm, bn, kBeg + ((ts+1)<<5), As1, Bs1, w, srow, scol);  // in flight during MFMA
        compute128(As0, Bs0, wm, wn, quad, l16, acc);
        __syncthreads();
        if (ts + 2 < nt)
            stage128(A, W, K, bm, bn, kBeg + ((ts+2)<<5), As0, Bs0, w, srow, scol);
        compute128(As1, Bs1, wm, wn, quad, l16, acc);
        __syncthreads();
    }
}

// ---------------- generic GEMM (outproj / FF1): C = A * Wb^T + bias (+epilogue) ----
__global__ __launch_bounds__(256) void gemm_mfma_kernel(
    const __hip_bfloat16* __restrict__ A, const __hip_bfloat16* __restrict__ Wb,
    const float* __restrict__ bias, int biasOff,
    const float* __restrict__ residIn, const float* __restrict__ residF,
    float* __restrict__ Cf, __hip_bfloat16* __restrict__ Cb,
    int M, int N, int K, int gelu)
{
    __shared__ __hip_bfloat16 As0[BM*BK], Bs0[BN*BK], As1[BM*BK], Bs1[BN*BK];
    int bm = blockIdx.y * BM, bn = blockIdx.x * BN;
    f32x4 acc[4][4];
    #pragma unroll
    for (int i=0;i<4;i++)
        #pragma unroll
        for (int j=0;j<4;j++) acc[i][j] = (f32x4){0.f,0.f,0.f,0.f};

    gemm_loop(A, Wb, K, bm, bn, 0, K, As0, Bs0, As1, Bs1, acc);

    const int t = threadIdx.x;
    const int w = t >> 6, lane = t & 63;
    const int quad = lane >> 4, l16 = lane & 15;
    const int wm = (w >> 1) * 64, wn = (w & 1) * 64;
    // C/D layout: col = lane&15, row = quad*4 + reg   [m89-verified]
    #pragma unroll
    for (int i=0;i<4;i++){
        #pragma unroll
        for (int j=0;j<4;j++){
            int colg = bn + wn + 16*j + l16;
            float bv = bias[biasOff + colg];
            #pragma unroll
            for (int r=0;r<4;r++){
                int rowg = bm + wm + 16*i + quad*4 + r;
                float vv = acc[i][j][r] + bv;
                if (gelu) vv = 0.5f*vv*(1.f + erff(vv*0.70710678118654752f));
                size_t idx = (size_t)rowg*N + colg;
                if (residIn) vv += residIn[idx];
                if (residF)  vv += residF[idx];
                if (Cf) Cf[idx] = vv;
                if (Cb) Cb[idx] = __float2bfloat16(vv);
            }
        }
    }
}

// ---------------- FF2 split-K: grid (8,32,2); z owns K half ----------------
// z=0: out = acc + bias + x1 (residual). z=1: f32 partial to chunked buffers
// (rows [0,2048) -> pA, rows [2048,4096) -> pB). Fused by addpart_kernel.
__global__ __launch_bounds__(256) void ff2_kernel(
    const __hip_bfloat16* __restrict__ A, const __hip_bfloat16* __restrict__ Wb,
    const float* __restrict__ bias, const float* __restrict__ resid,
    float* __restrict__ out, float* __restrict__ pA, float* __restrict__ pB)
{
    __shared__ __hip_bfloat16 As0[BM*BK], Bs0[BN*BK], As1[BM*BK], Bs1[BN*BK];
    int bm = blockIdx.y * BM, bn = blockIdx.x * BN, z = blockIdx.z;
    f32x4 acc[4][4];
    #pragma unroll
    for (int i=0;i<4;i++)
        #pragma unroll
        for (int j=0;j<4;j++) acc[i][j] = (f32x4){0.f,0.f,0.f,0.f};

    gemm_loop(A, Wb, FFD, bm, bn, z*2048, (z+1)*2048, As0, Bs0, As1, Bs1, acc);

    const int t = threadIdx.x;
    const int w = t >> 6, lane = t & 63;
    const int quad = lane >> 4, l16 = lane & 15;
    const int wm = (w >> 1) * 64, wn = (w & 1) * 64;
    #pragma unroll
    for (int i=0;i<4;i++){
        #pragma unroll
        for (int j=0;j<4;j++){
            int colg = bn + wn + 16*j + l16;
            float bv = bias[colg];
            #pragma unroll
            for (int r=0;r<4;r++){
                int rowg = bm + wm + 16*i + quad*4 + r;
                size_t idx = (size_t)rowg*D + colg;
                if (z == 0){
                    out[idx] = acc[i][j][r] + bv + resid[idx];
                } else {
                    if (rowg < 2048) pA[idx] = acc[i][j][r];
                    else             pB[idx - (size_t)2048*D] = acc[i][j][r];
                }
            }
        }
    }
}

// ---------------- vectorized dst += (a|b) fuse ----------------
__global__ __launch_bounds__(256) void addpart_kernel(
    float* __restrict__ dst, const float* __restrict__ a, const float* __restrict__ b,
    long n4, long split4)
{
    for (long i = (long)blockIdx.x*256 + threadIdx.x; i < n4; i += (long)gridDim.x*256){
        float4 d = ((float4*)dst)[i];
        float4 s = (i < split4) ? ((const float4*)a)[i] : ((const float4*)b)[i - split4];
        d.x += s.x; d.y += s.y; d.z += s.z; d.w += s.w;
        ((float4*)dst)[i] = d;
    }
}

// ---------------- merged QKV projection: one dispatch, 1280 blocks (~5/CU) -------------
__global__ __launch_bounds__(256) void qkv_kernel(
    const __hip_bfloat16* __restrict__ qln, const __hip_bfloat16* __restrict__ kvln,
    const __hip_bfloat16* __restrict__ wip, const float* __restrict__ ipb,
    __hip_bfloat16* __restrict__ qb, __hip_bfloat16* __restrict__ kb,
    __hip_bfloat16* __restrict__ vbT)
{
    __shared__ __hip_bfloat16 As0[BM*BK], Bs0[BN*BK], As1[BM*BK], Bs1[BN*BK];
    int id = blockIdx.x;
    const __hip_bfloat16 *A, *W;
    int bm, bn, isq;
    if (id < 1024){ isq = 0; A = kvln; W = wip + (size_t)D*D; bn = (id & 15)*BN; bm = (id >> 4)*BM; }
    else { int qid = id - 1024; isq = 1; A = qln; W = wip; bn = (qid & 7)*BN; bm = (qid >> 3)*BM; }

    f32x4 acc[4][4];
    #pragma unroll
    for (int i=0;i<4;i++)
        #pragma unroll
        for (int j=0;j<4;j++) acc[i][j] = (f32x4){0.f,0.f,0.f,0.f};

    gemm_loop(A, W, 1024, bm, bn, 0, 1024, As0, Bs0, As1, Bs1, acc);

    const int t = threadIdx.x;
    const int w = t >> 6, lane = t & 63;
    const int quad = lane >> 4, l16 = lane & 15;
    const int wm = (w >> 1) * 64, wn = (w & 1) * 64;
    #pragma unroll
    for (int i=0;i<4;i++){
        #pragma unroll
        for (int j=0;j<4;j++){
            int colg = bn + wn + 16*j + l16;
            float bv = ipb[(isq ? 0 : D) + colg];
            if (isq){
                #pragma unroll
                for (int r=0;r<4;r++){
                    int rowg = bm + wm + 16*i + quad*4 + r;
                    qb[(size_t)rowg*D + colg] = __float2bfloat16(acc[i][j][r] + bv);
                }
            } else if (colg < 1024){
                #pragma unroll
                for (int r=0;r<4;r++){
                    int rowg = bm + wm + 16*i + quad*4 + r;
                    kb[(size_t)rowg*D + colg] = __float2bfloat16(acc[i][j][r] + bv);
                }
            } else {
                // V head-transposed: vbT[((b*NH+h)*HD+d)*NKV + kv], 4 consecutive kv packed
                union { unsigned short u[4]; short4 s4; } pk;
                #pragma unroll
                for (int r=0;r<4;r++) pk.u[r] = f2bbits(acc[i][j][r] + bv);
                int rowg0 = bm + wm + 16*i + quad*4;     // kv-token row, multiple of 4
                int bb = rowg0 >> 10, kvi = rowg0 & 1023;
                int c = colg - 1024, hh = c >> 6, dd = c & 63;
                *(short4*)&vbT[(((size_t)bb*NH + hh)*HD + dd)*NKV + kvi] = pk.s4;
            }
        }
    }
}

// ---------------- MFMA attention, head-split x2 for occupancy ----------------
// grid (BATCH, NQ/16, 2); 512 thr = 8 waves; block handles 8 heads.
// 2 blocks/CU (fits VGPR cap of 16 waves/CU at VGPR=72 and LDS 2x39.4KB).
// attn_mean: z=0 writes its 8-head partial direct to out_attn; z=1 to a free
// workspace buffer; addpart_kernel fuses. ctx writes are head-disjoint (no fuse).
// Barriers: 3/head (B1 max-red, B2 sum-red + P visible, B3 pvred + P reads done).
#define QT 16
#define HSPLIT 2
#define HPB (NH/HSPLIT)
#define PLD (NKV + 8)    // P row stride (elements); 2064B rows de-stride LDS banks
__global__ __launch_bounds__(512) void attn_kernel(
    const __hip_bfloat16* __restrict__ q, const __hip_bfloat16* __restrict__ k,
    const __hip_bfloat16* __restrict__ vt, const void* __restrict__ mask,
    __hip_bfloat16* __restrict__ ctx, float* __restrict__ attn_out,
    float* __restrict__ attn_part)
{
    const int t = threadIdx.x;
    const int w = t >> 6;            // wave 0..7
    const int lane = t & 63;
    const int g = lane >> 4;         // quad
    const int l16 = lane & 15;       // q-row for S^T / P / PV-cols
    const int b  = blockIdx.x;       // batch on grid.x -> XCD-local K/V
    const int q0 = blockIdx.y * QT;
    const int h0 = blockIdx.z * HPB;

    __shared__ __hip_bfloat16 P[QT*PLD];     // P[q][kv]
    __shared__ float pvred[4*16*20];         // [mt][q][d-pad20] partial ctx^T (kv-half 1)
    __shared__ float red1[8*16];             // per-wave row max
    __shared__ float red2[8*16];             // per-wave row sum
    __shared__ int m8s;

    if (t==0) m8s = 0;
    __syncthreads();
    if (t < 256){ unsigned wd = ((const unsigned*)mask)[t]; if (wd > 1u) atomicOr(&m8s, 1); }
    __syncthreads();
    const bool m8 = m8s != 0;

    // per-lane mask bits: kv = w*128 + kt*16 + 4*g + r  (matches S^T register layout)
    unsigned mbits = 0;
    #pragma unroll
    for (int kt=0;kt<8;kt++){
        #pragma unroll
        for (int r=0;r<4;r++){
            size_t mi = (size_t)b*NKV + w*128 + kt*16 + 4*g + r;
            int mv = m8 ? (int)((const unsigned char*)mask)[mi] : ((const int*)mask)[mi];
            if (mv) mbits |= (1u << (kt*4+r));
        }
    }

    float amean[8][4];
    #pragma unroll
    for (int kt=0;kt<8;kt++)
        #pragma unroll
        for (int r=0;r<4;r++) amean[kt][r] = 0.f;

    const int mt = w >> 1;           // PV: d-tile 0..3
    const int kvh = w & 1;           // PV: kv half
    const __hip_bfloat16* qrow = &q[((size_t)(b*NQ + q0 + l16))*D];

    for (int hh=0; hh<HPB; hh++){
        const int h = h0 + hh;
        // ---- S^T = K @ Q^T  (per wave: 8 kv-tiles x K=64) ----
        bf16x8 bq0 = *(const bf16x8*)&qrow[h*HD + g*8];
        bf16x8 bq1 = *(const bf16x8*)&qrow[h*HD + 32 + g*8];
        f32x4 s[8];
        #pragma unroll
        for (int kt=0;kt<8;kt++){
            const __hip_bfloat16* kp = &k[((size_t)(b*NKV + w*128 + kt*16 + l16))*D + h*HD];
            bf16x8 a0 = *(const bf16x8*)&kp[g*8];
            bf16x8 a1 = *(const bf16x8*)&kp[32 + g*8];
            f32x4 z = (f32x4){0.f,0.f,0.f,0.f};
            z = __builtin_amdgcn_mfma_f32_16x16x32_bf16(a0, bq0, z, 0, 0, 0);
            z = __builtin_amdgcn_mfma_f32_16x16x32_bf16(a1, bq1, z, 0, 0, 0);
            s[kt] = z;
        }
        // ---- scale + mask + row max ----
        float lmax = -3.0e38f;
        #pragma unroll
        for (int kt=0;kt<8;kt++){
            #pragma unroll
            for (int r=0;r<4;r++){
                float sv = ((mbits >> (kt*4+r)) & 1u) ? -3.0e38f : s[kt][r]*0.125f;
                s[kt][r] = sv;
                lmax = fmaxf(lmax, sv);
            }
        }
        lmax = fmaxf(lmax, __shfl_xor(lmax, 16));
        lmax = fmaxf(lmax, __shfl_xor(lmax, 32));
        if (lane < 16) red1[w*16 + l16] = lmax;
        __syncthreads();                       // B1: max reduction
        float m = red1[l16];
        #pragma unroll
        for (int w2=1; w2<8; w2++) m = fmaxf(m, red1[w2*16 + l16]);
        // ---- exp + P-write (unnormalized bf16) + row sum ----
        float lsum = 0.f;
        #pragma unroll
        for (int kt=0;kt<8;kt++){
            union { unsigned short u[4]; short4 s4; } pk;
            #pragma unroll
            for (int r=0;r<4;r++){
                float e = __expf(s[kt][r] - m);
                s[kt][r] = e;
                lsum += e;
                pk.u[r] = f2bbits(e);
            }
            *(short4*)&P[l16*PLD + w*128 + kt*16 + 4*g] = pk.s4;
        }
        lsum += __shfl_xor(lsum, 16);
        lsum += __shfl_xor(lsum, 32);
        if (lane < 16) red2[w*16 + l16] = lsum;
        __syncthreads();                       // B2: sum reduction + P visible
        float tot = red2[l16];
        #pragma unroll
        for (int w2=1; w2<8; w2++) tot += red2[w2*16 + l16];
        float inv = 1.f/tot;
        float ai  = inv * (1.f/NH);
        #pragma unroll
        for (int kt=0;kt<8;kt++)
            #pragma unroll
            for (int r=0;r<4;r++) amean[kt][r] += s[kt][r]*ai;
        // ---- PV: ctx^T[d,q] = V^T[d,:] @ P[q,:]^T ; wave = (d-tile mt, kv-half kvh) ----
        f32x4 pv = (f32x4){0.f,0.f,0.f,0.f};
        const __hip_bfloat16* vrow = &vt[(((size_t)(b*NH + h))*HD + mt*16 + l16)*NKV + kvh*512];
        #pragma unroll
        for (int ks=0;ks<16;ks++){
            bf16x8 av = *(const bf16x8*)&vrow[ks*32 + g*8];
            bf16x8 bp = *(const bf16x8*)&P[l16*PLD + kvh*512 + ks*32 + g*8];
            pv = __builtin_amdgcn_mfma_f32_16x16x32_bf16(av, bp, pv, 0, 0, 0);
        }
        if (kvh){
            *(f32x4*)&pvred[(mt*16 + l16)*20 + 4*g] = pv;
        }
        __syncthreads();                       // B3: pvred visible; P reads done
        if (!kvh){
            const f32x4 other = *(const f32x4*)&pvred[(mt*16 + l16)*20 + 4*g];
            union { unsigned short u[4]; short4 s4; } pk;
            #pragma unroll
            for (int r=0;r<4;r++) pk.u[r] = f2bbits((pv[r] + other[r]) * inv);
            *(short4*)&ctx[((size_t)(b*NQ + q0 + l16))*D + h*HD + mt*16 + 4*g] = pk.s4;
        }
        // next head's red1 write is safe: this head's red1 reads consumed before B2
    }
    // ---- attn-mean partial write (f32, one pass, no atomics) ----
    float* dst = (blockIdx.z == 0) ? attn_out : attn_part;
    float* ao = dst + ((size_t)(b*NQ + q0 + l16))*NKV;
    #pragma unroll
    for (int kt=0;kt<8;kt++){
        float4 v4 = make_float4(amean[kt][0], amean[kt][1], amean[kt][2], amean[kt][3]);
        *(float4*)&ao[w*128 + kt*16 + 4*g] = v4;
    }
}

// ---------------- sentinel fill ----------------
__global__ __launch_bounds__(256) void fill_f32_kernel(float* __restrict__ p, float val, long n){
    size_t i = (size_t)blockIdx.x*256 + threadIdx.x;
    if ((long)i < n) p[i] = val;
}

extern "C" void kernel_launch(void* const* d_in, const int* in_sizes, int n_in,
                              void* d_out, int out_size, void* d_ws, size_t ws_size,
                              hipStream_t stream)
{
    const float* query     = (const float*)d_in[0];
    const float* key_value = (const float*)d_in[1];
    const void*  mask      = d_in[2];
    const float* nq_gamma  = (const float*)d_in[3];
    const float* nq_beta   = (const float*)d_in[4];
    const float* nkv_gamma = (const float*)d_in[5];
    const float* nkv_beta  = (const float*)d_in[6];
    const float* ipw       = (const float*)d_in[7];
    const float* ipb       = (const float*)d_in[8];
    const float* out_w     = (const float*)d_in[9];
    const float* out_b     = (const float*)d_in[10];
    const float* nffg      = (const float*)d_in[11];
    const float* nffb      = (const float*)d_in[12];
    const float* ff1w      = (const float*)d_in[13];
    const float* ff1b      = (const float*)d_in[14];
    const float* ff2w      = (const float*)d_in[15];
    const float* ff2b      = (const float*)d_in[16];

    float* out_x = (float*)d_out;
    // ---- host-side shape checks (proven in r6/r8; keep as guard) ----
    long Dn  = (n_in > 3)  ? in_sizes[3]  : 0;
    long FFn = (n_in > 14) ? in_sizes[14] : 0;
    long Rq=0, Rkv=0, Nkvd=0, Bd=0, Nqd=0;
    auto derive = [&](long Sq_, long Skv_)->bool{
        if (Dn <= 0 || Sq_ <= 0 || Skv_ <= 0) return false;
        if (Sq_ % Dn || Skv_ % Dn) return false;
        Rq = Sq_/Dn; Rkv = Skv_/Dn;
        long num = (long)out_size - Rq*Dn;
        if (Rq <= 0 || num <= 0 || num % Rq) return false;
        Nkvd = num / Rq;
        if (Nkvd <= 0 || Rkv % Nkvd) return false;
        Bd = Rkv / Nkvd;
        if (Bd <= 0 || Rq % Bd) return false;
        Nqd = Rq / Bd;
        if ((long)in_sizes[2] != Rkv) return false;
        return true;
    };
    int sentinel = 0;
    if (n_in != 17) sentinel = 600;
    else if (!derive(in_sizes[0], in_sizes[1])) sentinel = 300;
    if (!sentinel && !(Dn==1024 && FFn==4096 && Bd==8 && Nqd==512 && Nkvd==1024)) sentinel = 500;
    if (!sentinel && ws_size < ((size_t)88<<20)) sentinel = 400;
    if (sentinel){
        long n = out_size;
        fill_f32_kernel<<<(unsigned)((n+255)/256), 256, 0, stream>>>(out_x, (float)sentinel, n);
        return;
    }

    float* out_attn = out_x + (size_t)BATCH*NQ*D;

    // Workspace map (bytes), peak 88 MB, lifetimes checked:
    //  [0,6)   wip bf16 (3M)      live all launch
    //  [6,8)   wout bf16 (1M)     live all launch
    //  [8,16)  wff1 bf16 (4M)     live all launch
    //  [16,24) wff2 bf16 (4M)     live all launch
    //  [24,32) qln bf16  -> dead after qkv    -> ctx bf16 (attn) -> dead after outproj -> ff2 partial pA
    //  [32,48) kvln bf16 -> dead after qkv    -> attn_part f32 (attn+fuse) -> x1 f32 (outproj)
    //  [48,56) qb bf16   -> dead after attn   -> hln bf16 -> dead after ff1 -> ff2 partial pB
    //  [56,72) kb bf16   -> dead after attn   -> hge bf16 lower
    //  [72,88) vbT bf16  -> dead after attn   -> hge bf16 upper
    char* Wc = (char*)d_ws;
    __hip_bfloat16* wip  = (__hip_bfloat16*)(Wc);
    __hip_bfloat16* wout = (__hip_bfloat16*)(Wc + ((size_t)6<<20));
    __hip_bfloat16* wff1 = (__hip_bfloat16*)(Wc + ((size_t)8<<20));
    __hip_bfloat16* wff2 = (__hip_bfloat16*)(Wc + ((size_t)16<<20));
    __hip_bfloat16* qln  = (__hip_bfloat16*)(Wc + ((size_t)24<<20));
    __hip_bfloat16* kvln = (__hip_bfloat16*)(Wc + ((size_t)32<<20));
    __hip_bfloat16* qb   = (__hip_bfloat16*)(Wc + ((size_t)48<<20));
    __hip_bfloat16* kb   = (__hip_bfloat16*)(Wc + ((size_t)56<<20));
    __hip_bfloat16* vbT  = (__hip_bfloat16*)(Wc + ((size_t)72<<20));
    __hip_bfloat16* ctx  = (__hip_bfloat16*)(Wc + ((size_t)24<<20));
    float* attn_part     = (float*)(Wc + ((size_t)32<<20));      // 16MB, then x1
    float*          x1   = (float*)(Wc + ((size_t)32<<20));
    __hip_bfloat16* hln  = (__hip_bfloat16*)(Wc + ((size_t)48<<20));
    float* ff2pA         = (float*)(Wc + ((size_t)24<<20));      // rows [0,2048)
    float* ff2pB         = (float*)(Wc + ((size_t)48<<20));      // rows [2048,4096)
    __hip_bfloat16* hge  = (__hip_bfloat16*)(Wc + ((size_t)56<<20));

    // 0) weight conversion f32->bf16
    cvt_w_kernel<<<(3*1024*1024+255)/256, 256, 0, stream>>>(ipw,  wip,  3*1024*1024);
    cvt_w_kernel<<<(1024*1024+255)/256,   256, 0, stream>>>(out_w, wout, 1024*1024);
    cvt_w_kernel<<<(4*1024*1024+255)/256, 256, 0, stream>>>(ff1w, wff1, 4*1024*1024);
    cvt_w_kernel<<<(4*1024*1024+255)/256, 256, 0, stream>>>(ff2w, wff2, 4*1024*1024);
    // 1) LayerNorms -> bf16
    ln_kernel<<<BATCH*NQ,  256, 0, stream>>>(query,     nq_gamma,  nq_beta,  qln);
    ln_kernel<<<BATCH*NKV, 256, 0, stream>>>(key_value, nkv_gamma, nkv_beta, kvln);
    // 2) merged QKV projection (1280 blocks; V written head-transposed [b][h][d][kv])
    qkv_kernel<<<1280, 256, 0, stream>>>(qln, kvln, wip, ipb, qb, kb, vbT);
    // 3) Attention head-split x2 (no atomics); fuse attn-mean partials
    attn_kernel<<<dim3(BATCH, NQ/QT, HSPLIT), 512, 0, stream>>>(qb, kb, vbT, mask, ctx, out_attn, attn_part);
    addpart_kernel<<<2048, 256, 0, stream>>>(out_attn, attn_part, attn_part,
                                             (long)BATCH*NQ*NKV/4, (long)BATCH*NQ*NKV/4);
    // 4) Output projection + residual(query) -> x1 f32   (overwrites attn_part region)
    gemm_mfma_kernel<<<dim3(8,32),  256, 0, stream>>>(ctx, wout, out_b, 0, query, nullptr, x1, nullptr, 4096, 1024, 1024, 0);
    // 5) FFN LN -> hln bf16
    ln_kernel<<<4096, 256, 0, stream>>>(x1, nffg, nffb, hln);
    // 6) FF1 + GELU -> hge bf16
    gemm_mfma_kernel<<<dim3(32,32), 256, 0, stream>>>(hln, wff1, ff1b, 0, nullptr, nullptr, nullptr, hge, 4096, 4096, 1024, 1);
    // 7) FF2 split-K (z0: +bias+x1 -> out_x; z1: partial), then fuse
    ff2_kernel<<<dim3(8,32,2), 256, 0, stream>>>(hge, wff2, ff2b, x1, out_x, ff2pA, ff2pB);
    addpart_kernel<<<2048, 256, 0, stream>>>(out_x, ff2pA, ff2pB,
                                             (long)4096*1024/4, (long)2048*1024/4);
}

// Round 13
// 575.136 us; speedup vs baseline: 1.3399x; 1.0389x over previous
//
#include <hip/hip_runtime.h>
#include <hip/hip_bf16.h>
#include <math.h>

#define D    1024
#define NQ   512
#define NKV  1024
#define BATCH 8
#define NH   16
#define HD   64
#define FFD  4096

typedef short bf16x8 __attribute__((ext_vector_type(8)));   // 8 bf16 (4 VGPRs)
typedef float f32x4  __attribute__((ext_vector_type(4)));

static __device__ __forceinline__ float bf2f(__hip_bfloat16 x){ return __bfloat162float(x); }
static __device__ __forceinline__ unsigned short f2bbits(float f){
    __hip_bfloat16 h = __float2bfloat16(f);
    return *(unsigned short*)&h;
}

// async global->LDS, 16B per lane; LDS dest = wave-uniform base + lane*16 (HW).
static __device__ __forceinline__ void gload_lds16(const __hip_bfloat16* g, __hip_bfloat16* l){
    __builtin_amdgcn_global_load_lds(
        (const __attribute__((address_space(1))) void*)g,
        (__attribute__((address_space(3))) void*)l,
        16, 0, 0);
}

// ---------------- f32 -> bf16 weight conversion ----------------
__global__ __launch_bounds__(256) void cvt_w_kernel(const float* __restrict__ in,
                                                    __hip_bfloat16* __restrict__ out, int n)
{
    int i = blockIdx.x*256 + threadIdx.x;
    if (i < n) out[i] = __float2bfloat16(in[i]);
}

// ---------------- LayerNorm (f32 in -> bf16 out), 256 thr, row = 1024 ----------------
__global__ __launch_bounds__(256) void ln_kernel(
    const float* __restrict__ x, const float* __restrict__ gamma, const float* __restrict__ beta,
    __hip_bfloat16* __restrict__ out)
{
    int row = blockIdx.x, t = threadIdx.x;
    __shared__ float wsum[4];
    __shared__ float stat[2];
    float4 v = *(const float4*)&x[(size_t)row*D + t*4];
    float s = v.x+v.y+v.z+v.w;
    #pragma unroll
    for (int o=32;o>0;o>>=1) s += __shfl_down(s, o);
    if ((t&63)==0) wsum[t>>6] = s;
    __syncthreads();
    if (t==0) stat[0] = (wsum[0]+wsum[1]+wsum[2]+wsum[3])*(1.f/D);
    __syncthreads();
    float mu = stat[0];
    float d0=v.x-mu, d1=v.y-mu, d2=v.z-mu, d3=v.w-mu;
    float s2 = d0*d0+d1*d1+d2*d2+d3*d3;
    #pragma unroll
    for (int o=32;o>0;o>>=1) s2 += __shfl_down(s2, o);
    if ((t&63)==0) wsum[t>>6] = s2;
    __syncthreads();
    if (t==0) stat[1] = rsqrtf((wsum[0]+wsum[1]+wsum[2]+wsum[3])*(1.f/D) + 1e-5f);
    __syncthreads();
    float rs = stat[1];
    const float4 g = *(const float4*)&gamma[t*4];
    const float4 b = *(const float4*)&beta[t*4];
    union { unsigned short u[4]; short4 s4; } pk;
    pk.u[0]=f2bbits(d0*rs*g.x+b.x); pk.u[1]=f2bbits(d1*rs*g.y+b.y);
    pk.u[2]=f2bbits(d2*rs*g.z+b.z); pk.u[3]=f2bbits(d3*rs*g.w+b.w);
    *(short4*)&out[(size_t)row*D + t*4] = pk.s4;
}

// ---------------- MFMA GEMM core: 128x128 tile, BK=32, 4 waves, DOUBLE-BUFFERED ----------
#define BM 128
#define BN 128
#define BK 32

static __device__ __forceinline__ void stage128(
    const __hip_bfloat16* __restrict__ A, const __hip_bfloat16* __restrict__ W,
    int K, int bm, int bn, int k0,
    __hip_bfloat16* as, __hip_bfloat16* bs, int w, int srow, int scol)
{
    #pragma unroll
    for (int rep=0; rep<2; rep++){
        int ti = (w<<1) + rep;   // wave-uniform 0..7; instr covers 16 rows x 32 cols
        gload_lds16(&A[(size_t)(bm + ti*16 + srow)*K + k0 + scol], &as[ti*16*BK]);
        gload_lds16(&W[(size_t)(bn + ti*16 + srow)*K + k0 + scol], &bs[ti*16*BK]);
    }
}

static __device__ __forceinline__ void compute128(
    const __hip_bfloat16* as, const __hip_bfloat16* bs,
    int wm, int wn, int quad, int l16, f32x4 acc[4][4])
{
    bf16x8 af[4], bfr[4];
    #pragma unroll
    for (int i=0;i<4;i++) af[i]  = *(const bf16x8*)&as[(wm + 16*i + l16)*BK + quad*8];
    #pragma unroll
    for (int j=0;j<4;j++) bfr[j] = *(const bf16x8*)&bs[(wn + 16*j + l16)*BK + quad*8];
    #pragma unroll
    for (int i=0;i<4;i++)
        #pragma unroll
        for (int j=0;j<4;j++)
            acc[i][j] = __builtin_amdgcn_mfma_f32_16x16x32_bf16(af[i], bfr[j], acc[i][j], 0, 0, 0);
}

// K-range [kBeg,kEnd) of a row-major K-stride matrix pair; supports split-K.
static __device__ __forceinline__ void gemm_loop(
    const __hip_bfloat16* __restrict__ A, const __hip_bfloat16* __restrict__ W,
    int K, int bm, int bn, int kBeg, int kEnd,
    __hip_bfloat16* As0, __hip_bfloat16* Bs0, __hip_bfloat16* As1, __hip_bfloat16* Bs1,
    f32x4 acc[4][4])
{
    const int t = threadIdx.x;
    const int w = t >> 6, lane = t & 63;
    const int quad = lane >> 4, l16 = lane & 15;
    const int wm = (w >> 1) * 64, wn = (w & 1) * 64;
    const int srow = lane >> 2, scol = (lane & 3) << 3;

    stage128(A, W, K, bm, bn, kBeg, As0, Bs0, w, srow, scol);
    __syncthreads();
    const int nt = (kEnd - kBeg) >> 5;     // even for all our shapes
    for (int ts = 0; ts < nt; ts += 2){
        stage128(A, W, K, bm, bn, kBeg + ((ts+1)<<5), As1, Bs1, w, srow, scol);  // in flight during MFMA
        compute128(As0, Bs0, wm, wn, quad, l16, acc);
        __syncthreads();
        if (ts + 2 < nt)
            stage128(A, W, K, bm, bn, kBeg + ((ts+2)<<5), As0, Bs0, w, srow, scol);
        compute128(As1, Bs1, wm, wn, quad, l16, acc);
        __syncthreads();
    }
}

// ---------------- generic GEMM (outproj / FF1): C = A * Wb^T + bias (+epilogue) ----
__global__ __launch_bounds__(256) void gemm_mfma_kernel(
    const __hip_bfloat16* __restrict__ A, const __hip_bfloat16* __restrict__ Wb,
    const float* __restrict__ bias, int biasOff,
    const float* __restrict__ residIn, const float* __restrict__ residF,
    float* __restrict__ Cf, __hip_bfloat16* __restrict__ Cb,
    int M, int N, int K, int gelu)
{
    __shared__ __hip_bfloat16 As0[BM*BK], Bs0[BN*BK], As1[BM*BK], Bs1[BN*BK];
    int bm = blockIdx.y * BM, bn = blockIdx.x * BN;
    f32x4 acc[4][4];
    #pragma unroll
    for (int i=0;i<4;i++)
        #pragma unroll
        for (int j=0;j<4;j++) acc[i][j] = (f32x4){0.f,0.f,0.f,0.f};

    gemm_loop(A, Wb, K, bm, bn, 0, K, As0, Bs0, As1, Bs1, acc);

    const int t = threadIdx.x;
    const int w = t >> 6, lane = t & 63;
    const int quad = lane >> 4, l16 = lane & 15;
    const int wm = (w >> 1) * 64, wn = (w & 1) * 64;
    // C/D layout: col = lane&15, row = quad*4 + reg   [m89-verified]
    #pragma unroll
    for (int i=0;i<4;i++){
        #pragma unroll
        for (int j=0;j<4;j++){
            int colg = bn + wn + 16*j + l16;
            float bv = bias[biasOff + colg];
            #pragma unroll
            for (int r=0;r<4;r++){
                int rowg = bm + wm + 16*i + quad*4 + r;
                float vv = acc[i][j][r] + bv;
                if (gelu) vv = 0.5f*vv*(1.f + erff(vv*0.70710678118654752f));
                size_t idx = (size_t)rowg*N + colg;
                if (residIn) vv += residIn[idx];
                if (residF)  vv += residF[idx];
                if (Cf) Cf[idx] = vv;
                if (Cb) Cb[idx] = __float2bfloat16(vv);
            }
        }
    }
}

// ---------------- FF2 split-K: grid (8,32,2); z owns K half ----------------
__global__ __launch_bounds__(256) void ff2_kernel(
    const __hip_bfloat16* __restrict__ A, const __hip_bfloat16* __restrict__ Wb,
    const float* __restrict__ bias, const float* __restrict__ resid,
    float* __restrict__ out, float* __restrict__ pA, float* __restrict__ pB)
{
    __shared__ __hip_bfloat16 As0[BM*BK], Bs0[BN*BK], As1[BM*BK], Bs1[BN*BK];
    int bm = blockIdx.y * BM, bn = blockIdx.x * BN, z = blockIdx.z;
    f32x4 acc[4][4];
    #pragma unroll
    for (int i=0;i<4;i++)
        #pragma unroll
        for (int j=0;j<4;j++) acc[i][j] = (f32x4){0.f,0.f,0.f,0.f};

    gemm_loop(A, Wb, FFD, bm, bn, z*2048, (z+1)*2048, As0, Bs0, As1, Bs1, acc);

    const int t = threadIdx.x;
    const int w = t >> 6, lane = t & 63;
    const int quad = lane >> 4, l16 = lane & 15;
    const int wm = (w >> 1) * 64, wn = (w & 1) * 64;
    #pragma unroll
    for (int i=0;i<4;i++){
        #pragma unroll
        for (int j=0;j<4;j++){
            int colg = bn + wn + 16*j + l16;
            float bv = bias[colg];
            #pragma unroll
            for (int r=0;r<4;r++){
                int rowg = bm + wm + 16*i + quad*4 + r;
                size_t idx = (size_t)rowg*D + colg;
                if (z == 0){
                    out[idx] = acc[i][j][r] + bv + resid[idx];
                } else {
                    if (rowg < 2048) pA[idx] = acc[i][j][r];
                    else             pB[idx - (size_t)2048*D] = acc[i][j][r];
                }
            }
        }
    }
}

// ---------------- vectorized dst += (a|b) fuse ----------------
__global__ __launch_bounds__(256) void addpart_kernel(
    float* __restrict__ dst, const float* __restrict__ a, const float* __restrict__ b,
    long n4, long split4)
{
    for (long i = (long)blockIdx.x*256 + threadIdx.x; i < n4; i += (long)gridDim.x*256){
        float4 d = ((float4*)dst)[i];
        float4 s = (i < split4) ? ((const float4*)a)[i] : ((const float4*)b)[i - split4];
        d.x += s.x; d.y += s.y; d.z += s.z; d.w += s.w;
        ((float4*)dst)[i] = d;
    }
}

// ---------------- merged QKV projection: one dispatch, 1280 blocks (~5/CU) -------------
__global__ __launch_bounds__(256) void qkv_kernel(
    const __hip_bfloat16* __restrict__ qln, const __hip_bfloat16* __restrict__ kvln,
    const __hip_bfloat16* __restrict__ wip, const float* __restrict__ ipb,
    __hip_bfloat16* __restrict__ qb, __hip_bfloat16* __restrict__ kb,
    __hip_bfloat16* __restrict__ vbT)
{
    __shared__ __hip_bfloat16 As0[BM*BK], Bs0[BN*BK], As1[BM*BK], Bs1[BN*BK];
    int id = blockIdx.x;
    const __hip_bfloat16 *A, *W;
    int bm, bn, isq;
    if (id < 1024){ isq = 0; A = kvln; W = wip + (size_t)D*D; bn = (id & 15)*BN; bm = (id >> 4)*BM; }
    else { int qid = id - 1024; isq = 1; A = qln; W = wip; bn = (qid & 7)*BN; bm = (qid >> 3)*BM; }

    f32x4 acc[4][4];
    #pragma unroll
    for (int i=0;i<4;i++)
        #pragma unroll
        for (int j=0;j<4;j++) acc[i][j] = (f32x4){0.f,0.f,0.f,0.f};

    gemm_loop(A, W, 1024, bm, bn, 0, 1024, As0, Bs0, As1, Bs1, acc);

    const int t = threadIdx.x;
    const int w = t >> 6, lane = t & 63;
    const int quad = lane >> 4, l16 = lane & 15;
    const int wm = (w >> 1) * 64, wn = (w & 1) * 64;
    #pragma unroll
    for (int i=0;i<4;i++){
        #pragma unroll
        for (int j=0;j<4;j++){
            int colg = bn + wn + 16*j + l16;
            float bv = ipb[(isq ? 0 : D) + colg];
            if (isq){
                #pragma unroll
                for (int r=0;r<4;r++){
                    int rowg = bm + wm + 16*i + quad*4 + r;
                    qb[(size_t)rowg*D + colg] = __float2bfloat16(acc[i][j][r] + bv);
                }
            } else if (colg < 1024){
                #pragma unroll
                for (int r=0;r<4;r++){
                    int rowg = bm + wm + 16*i + quad*4 + r;
                    kb[(size_t)rowg*D + colg] = __float2bfloat16(acc[i][j][r] + bv);
                }
            } else {
                // V head-transposed: vbT[((b*NH+h)*HD+d)*NKV + kv], 4 consecutive kv packed
                union { unsigned short u[4]; short4 s4; } pk;
                #pragma unroll
                for (int r=0;r<4;r++) pk.u[r] = f2bbits(acc[i][j][r] + bv);
                int rowg0 = bm + wm + 16*i + quad*4;     // kv-token row, multiple of 4
                int bb = rowg0 >> 10, kvi = rowg0 & 1023;
                int c = colg - 1024, hh = c >> 6, dd = c & 63;
                *(short4*)&vbT[(((size_t)bb*NH + hh)*HD + dd)*NKV + kvi] = pk.s4;
            }
        }
    }
}

// ---------------- MFMA attention, head-split x2 for occupancy ----------------
// grid (BATCH, NQ/16, 2); 512 thr = 8 waves; block handles 8 heads.
// __launch_bounds__(512, 4): min 4 waves/EU -> allocator caps arch+acc regs at 128/wave
// so TWO 8-wave workgroups co-reside per CU (r6 post-mortem: ~72 arch + 64 acc = 136 > 128
// blocked the 2nd workgroup; LDS 2x39.4KB fits the 160KB pool).
// attn_mean: z=0 writes its 8-head partial direct to out_attn; z=1 to a free
// workspace buffer; addpart_kernel fuses. ctx writes are head-disjoint (no fuse).
#define QT 16
#define HSPLIT 2
#define HPB (NH/HSPLIT)
#define PLD (NKV + 8)    // P row stride (elements); 2064B rows de-stride LDS banks
__global__ __launch_bounds__(512, 4) void attn_kernel(
    const __hip_bfloat16* __restrict__ q, const __hip_bfloat16* __restrict__ k,
    const __hip_bfloat16* __restrict__ vt, const void* __restrict__ mask,
    __hip_bfloat16* __restrict__ ctx, float* __restrict__ attn_out,
    float* __restrict__ attn_part)
{
    const int t = threadIdx.x;
    const int w = t >> 6;            // wave 0..7
    const int lane = t & 63;
    const int g = lane >> 4;         // quad
    const int l16 = lane & 15;       // q-row for S^T / P / PV-cols
    const int b  = blockIdx.x;       // batch on grid.x -> XCD-local K/V
    const int q0 = blockIdx.y * QT;
    const int h0 = blockIdx.z * HPB;

    __shared__ __hip_bfloat16 P[QT*PLD];     // P[q][kv]
    __shared__ float pvred[4*16*20];         // [mt][q][d-pad20] partial ctx^T (kv-half 1)
    __shared__ float red1[8*16];             // per-wave row max
    __shared__ float red2[8*16];             // per-wave row sum
    __shared__ int m8s;

    if (t==0) m8s = 0;
    __syncthreads();
    if (t < 256){ unsigned wd = ((const unsigned*)mask)[t]; if (wd > 1u) atomicOr(&m8s, 1); }
    __syncthreads();
    const bool m8 = m8s != 0;

    // per-lane mask bits: kv = w*128 + kt*16 + 4*g + r  (matches S^T register layout)
    unsigned mbits = 0;
    #pragma unroll
    for (int kt=0;kt<8;kt++){
        #pragma unroll
        for (int r=0;r<4;r++){
            size_t mi = (size_t)b*NKV + w*128 + kt*16 + 4*g + r;
            int mv = m8 ? (int)((const unsigned char*)mask)[mi] : ((const int*)mask)[mi];
            if (mv) mbits |= (1u << (kt*4+r));
        }
    }

    float amean[8][4];
    #pragma unroll
    for (int kt=0;kt<8;kt++)
        #pragma unroll
        for (int r=0;r<4;r++) amean[kt][r] = 0.f;

    const int mt = w >> 1;           // PV: d-tile 0..3
    const int kvh = w & 1;           // PV: kv half
    const __hip_bfloat16* qrow = &q[((size_t)(b*NQ + q0 + l16))*D];

    for (int hh=0; hh<HPB; hh++){
        const int h = h0 + hh;
        // ---- S^T = K @ Q^T  (per wave: 8 kv-tiles x K=64) ----
        bf16x8 bq0 = *(const bf16x8*)&qrow[h*HD + g*8];
        bf16x8 bq1 = *(const bf16x8*)&qrow[h*HD + 32 + g*8];
        f32x4 s[8];
        #pragma unroll
        for (int kt=0;kt<8;kt++){
            const __hip_bfloat16* kp = &k[((size_t)(b*NKV + w*128 + kt*16 + l16))*D + h*HD];
            bf16x8 a0 = *(const bf16x8*)&kp[g*8];
            bf16x8 a1 = *(const bf16x8*)&kp[32 + g*8];
            f32x4 z = (f32x4){0.f,0.f,0.f,0.f};
            z = __builtin_amdgcn_mfma_f32_16x16x32_bf16(a0, bq0, z, 0, 0, 0);
            z = __builtin_amdgcn_mfma_f32_16x16x32_bf16(a1, bq1, z, 0, 0, 0);
            s[kt] = z;
        }
        // ---- scale + mask + row max ----
        float lmax = -3.0e38f;
        #pragma unroll
        for (int kt=0;kt<8;kt++){
            #pragma unroll
            for (int r=0;r<4;r++){
                float sv = ((mbits >> (kt*4+r)) & 1u) ? -3.0e38f : s[kt][r]*0.125f;
                s[kt][r] = sv;
                lmax = fmaxf(lmax, sv);
            }
        }
        lmax = fmaxf(lmax, __shfl_xor(lmax, 16));
        lmax = fmaxf(lmax, __shfl_xor(lmax, 32));
        if (lane < 16) red1[w*16 + l16] = lmax;
        __syncthreads();                       // B1: max reduction
        float m = red1[l16];
        #pragma unroll
        for (int w2=1; w2<8; w2++) m = fmaxf(m, red1[w2*16 + l16]);
        // ---- exp + P-write (unnormalized bf16) + row sum ----
        float lsum = 0.f;
        #pragma unroll
        for (int kt=0;kt<8;kt++){
            union { unsigned short u[4]; short4 s4; } pk;
            #pragma unroll
            for (int r=0;r<4;r++){
                float e = __expf(s[kt][r] - m);
                s[kt][r] = e;
                lsum += e;
                pk.u[r] = f2bbits(e);
            }
            *(short4*)&P[l16*PLD + w*128 + kt*16 + 4*g] = pk.s4;
        }
        lsum += __shfl_xor(lsum, 16);
        lsum += __shfl_xor(lsum, 32);
        if (lane < 16) red2[w*16 + l16] = lsum;
        __syncthreads();                       // B2: sum reduction + P visible
        float tot = red2[l16];
        #pragma unroll
        for (int w2=1; w2<8; w2++) tot += red2[w2*16 + l16];
        float inv = 1.f/tot;
        float ai  = inv * (1.f/NH);
        #pragma unroll
        for (int kt=0;kt<8;kt++)
            #pragma unroll
            for (int r=0;r<4;r++) amean[kt][r] += s[kt][r]*ai;
        // ---- PV: ctx^T[d,q] = V^T[d,:] @ P[q,:]^T ; wave = (d-tile mt, kv-half kvh) ----
        f32x4 pv = (f32x4){0.f,0.f,0.f,0.f};
        const __hip_bfloat16* vrow = &vt[(((size_t)(b*NH + h))*HD + mt*16 + l16)*NKV + kvh*512];
        #pragma unroll
        for (int ks=0;ks<16;ks++){
            bf16x8 av = *(const bf16x8*)&vrow[ks*32 + g*8];
            bf16x8 bp = *(const bf16x8*)&P[l16*PLD + kvh*512 + ks*32 + g*8];
            pv = __builtin_amdgcn_mfma_f32_16x16x32_bf16(av, bp, pv, 0, 0, 0);
        }
        if (kvh){
            *(f32x4*)&pvred[(mt*16 + l16)*20 + 4*g] = pv;
        }
        __syncthreads();                       // B3: pvred visible; P reads done
        if (!kvh){
            const f32x4 other = *(const f32x4*)&pvred[(mt*16 + l16)*20 + 4*g];
            union { unsigned short u[4]; short4 s4; } pk;
            #pragma unroll
            for (int r=0;r<4;r++) pk.u[r] = f2bbits((pv[r] + other[r]) * inv);
            *(short4*)&ctx[((size_t)(b*NQ + q0 + l16))*D + h*HD + mt*16 + 4*g] = pk.s4;
        }
        // next head's red1 write is safe: this head's red1 reads consumed before B2
    }
    // ---- attn-mean partial write (f32, one pass, no atomics) ----
    float* dst = (blockIdx.z == 0) ? attn_out : attn_part;
    float* ao = dst + ((size_t)(b*NQ + q0 + l16))*NKV;
    #pragma unroll
    for (int kt=0;kt<8;kt++){
        float4 v4 = make_float4(amean[kt][0], amean[kt][1], amean[kt][2], amean[kt][3]);
        *(float4*)&ao[w*128 + kt*16 + 4*g] = v4;
    }
}

// ---------------- sentinel fill ----------------
__global__ __launch_bounds__(256) void fill_f32_kernel(float* __restrict__ p, float val, long n){
    size_t i = (size_t)blockIdx.x*256 + threadIdx.x;
    if ((long)i < n) p[i] = val;
}

extern "C" void kernel_launch(void* const* d_in, const int* in_sizes, int n_in,
                              void* d_out, int out_size, void* d_ws, size_t ws_size,
                              hipStream_t stream)
{
    const float* query     = (const float*)d_in[0];
    const float* key_value = (const float*)d_in[1];
    const void*  mask      = d_in[2];
    const float* nq_gamma  = (const float*)d_in[3];
    const float* nq_beta   = (const float*)d_in[4];
    const float* nkv_gamma = (const float*)d_in[5];
    const float* nkv_beta  = (const float*)d_in[6];
    const float* ipw       = (const float*)d_in[7];
    const float* ipb       = (const float*)d_in[8];
    const float* out_w     = (const float*)d_in[9];
    const float* out_b     = (const float*)d_in[10];
    const float* nffg      = (const float*)d_in[11];
    const float* nffb      = (const float*)d_in[12];
    const float* ff1w      = (const float*)d_in[13];
    const float* ff1b      = (const float*)d_in[14];
    const float* ff2w      = (const float*)d_in[15];
    const float* ff2b      = (const float*)d_in[16];

    float* out_x = (float*)d_out;
    // ---- host-side shape checks (proven in r6/r8; keep as guard) ----
    long Dn  = (n_in > 3)  ? in_sizes[3]  : 0;
    long FFn = (n_in > 14) ? in_sizes[14] : 0;
    long Rq=0, Rkv=0, Nkvd=0, Bd=0, Nqd=0;
    auto derive = [&](long Sq_, long Skv_)->bool{
        if (Dn <= 0 || Sq_ <= 0 || Skv_ <= 0) return false;
        if (Sq_ % Dn || Skv_ % Dn) return false;
        Rq = Sq_/Dn; Rkv = Skv_/Dn;
        long num = (long)out_size - Rq*Dn;
        if (Rq <= 0 || num <= 0 || num % Rq) return false;
        Nkvd = num / Rq;
        if (Nkvd <= 0 || Rkv % Nkvd) return false;
        Bd = Rkv / Nkvd;
        if (Bd <= 0 || Rq % Bd) return false;
        Nqd = Rq / Bd;
        if ((long)in_sizes[2] != Rkv) return false;
        return true;
    };
    int sentinel = 0;
    if (n_in != 17) sentinel = 600;
    else if (!derive(in_sizes[0], in_sizes[1])) sentinel = 300;
    if (!sentinel && !(Dn==1024 && FFn==4096 && Bd==8 && Nqd==512 && Nkvd==1024)) sentinel = 500;
    if (!sentinel && ws_size < ((size_t)88<<20)) sentinel = 400;
    if (sentinel){
        long n = out_size;
        fill_f32_kernel<<<(unsigned)((n+255)/256), 256, 0, stream>>>(out_x, (float)sentinel, n);
        return;
    }

    float* out_attn = out_x + (size_t)BATCH*NQ*D;

    // Workspace map (bytes), peak 88 MB, lifetimes checked:
    //  [0,6)   wip bf16 (3M)      live all launch
    //  [6,8)   wout bf16 (1M)     live all launch
    //  [8,16)  wff1 bf16 (4M)     live all launch
    //  [16,24) wff2 bf16 (4M)     live all launch
    //  [24,32) qln bf16  -> dead after qkv    -> ctx bf16 (attn) -> dead after outproj -> ff2 partial pA
    //  [32,48) kvln bf16 -> dead after qkv    -> attn_part f32 (attn+fuse) -> x1 f32 (outproj)
    //  [48,56) qb bf16   -> dead after attn   -> hln bf16 -> dead after ff1 -> ff2 partial pB
    //  [56,72) kb bf16   -> dead after attn   -> hge bf16 lower
    //  [72,88) vbT bf16  -> dead after attn   -> hge bf16 upper
    char* Wc = (char*)d_ws;
    __hip_bfloat16* wip  = (__hip_bfloat16*)(Wc);
    __hip_bfloat16* wout = (__hip_bfloat16*)(Wc + ((size_t)6<<20));
    __hip_bfloat16* wff1 = (__hip_bfloat16*)(Wc + ((size_t)8<<20));
    __hip_bfloat16* wff2 = (__hip_bfloat16*)(Wc + ((size_t)16<<20));
    __hip_bfloat16* qln  = (__hip_bfloat16*)(Wc + ((size_t)24<<20));
    __hip_bfloat16* kvln = (__hip_bfloat16*)(Wc + ((size_t)32<<20));
    __hip_bfloat16* qb   = (__hip_bfloat16*)(Wc + ((size_t)48<<20));
    __hip_bfloat16* kb   = (__hip_bfloat16*)(Wc + ((size_t)56<<20));
    __hip_bfloat16* vbT  = (__hip_bfloat16*)(Wc + ((size_t)72<<20));
    __hip_bfloat16* ctx  = (__hip_bfloat16*)(Wc + ((size_t)24<<20));
    float* attn_part     = (float*)(Wc + ((size_t)32<<20));      // 16MB, then x1
    float*          x1   = (float*)(Wc + ((size_t)32<<20));
    __hip_bfloat16* hln  = (__hip_bfloat16*)(Wc + ((size_t)48<<20));
    float* ff2pA         = (float*)(Wc + ((size_t)24<<20));      // rows [0,2048)
    float* ff2pB         = (float*)(Wc + ((size_t)48<<20));      // rows [2048,4096)
    __hip_bfloat16* hge  = (__hip_bfloat16*)(Wc + ((size_t)56<<20));

    // 0) weight conversion f32->bf16
    cvt_w_kernel<<<(3*1024*1024+255)/256, 256, 0, stream>>>(ipw,  wip,  3*1024*1024);
    cvt_w_kernel<<<(1024*1024+255)/256,   256, 0, stream>>>(out_w, wout, 1024*1024);
    cvt_w_kernel<<<(4*1024*1024+255)/256, 256, 0, stream>>>(ff1w, wff1, 4*1024*1024);
    cvt_w_kernel<<<(4*1024*1024+255)/256, 256, 0, stream>>>(ff2w, wff2, 4*1024*1024);
    // 1) LayerNorms -> bf16
    ln_kernel<<<BATCH*NQ,  256, 0, stream>>>(query,     nq_gamma,  nq_beta,  qln);
    ln_kernel<<<BATCH*NKV, 256, 0, stream>>>(key_value, nkv_gamma, nkv_beta, kvln);
    // 2) merged QKV projection (1280 blocks; V written head-transposed [b][h][d][kv])
    qkv_kernel<<<1280, 256, 0, stream>>>(qln, kvln, wip, ipb, qb, kb, vbT);
    // 3) Attention head-split x2 (no atomics); fuse attn-mean partials
    attn_kernel<<<dim3(BATCH, NQ/QT, HSPLIT), 512, 0, stream>>>(qb, kb, vbT, mask, ctx, out_attn, attn_part);
    addpart_kernel<<<2048, 256, 0, stream>>>(out_attn, attn_part, attn_part,
                                             (long)BATCH*NQ*NKV/4, (long)BATCH*NQ*NKV/4);
    // 4) Output projection + residual(query) -> x1 f32   (overwrites attn_part region)
    gemm_mfma_kernel<<<dim3(8,32),  256, 0, stream>>>(ctx, wout, out_b, 0, query, nullptr, x1, nullptr, 4096, 1024, 1024, 0);
    // 5) FFN LN -> hln bf16
    ln_kernel<<<4096, 256, 0, stream>>>(x1, nffg, nffb, hln);
    // 6) FF1 + GELU -> hge bf16
    gemm_mfma_kernel<<<dim3(32,32), 256, 0, stream>>>(hln, wff1, ff1b, 0, nullptr, nullptr, nullptr, hge, 4096, 4096, 1024, 1);
    // 7) FF2 split-K (z0: +bias+x1 -> out_x; z1: partial), then fuse
    ff2_kernel<<<dim3(8,32,2), 256, 0, stream>>>(hge, wff2, ff2b, x1, out_x, ff2pA, ff2pB);
    addpart_kernel<<<2048, 256, 0, stream>>>(out_x, ff2pA, ff2pB,
                                             (long)4096*1024/4, (long)2048*1024/4);
}